// Round 6
// baseline (83.757 us; speedup 1.0000x reference)
//
#include <hip/hip_runtime.h>
#include <stdint.h>

#define NLEV   256
#define DIST   5
#define NB     64
#define NH     512
#define NW     512
#define PLANE  (NH*NW)            // 262144
#define NPAIRS (NH*(NW-DIST))     // 259584
#define NPARTS 4                  // 128 rows/part -> max 64896 pairs/bin < 65536 (u16-safe)

// ---------------------------------------------------------------------------
// K1 (fused gray+hist): grid = 64 batches x 4 parts, 1024 threads (16 waves,
// 4 waves/SIMD for HBM latency hiding at 1 WG/CU). One wave processes one
// full 512-px row per iteration: lane owns 8 px, computes gray indices in
// registers, gets the col+5 neighbor via __shfl, and does ONE packed-u16 LDS
// atomic per pair. 128KB LDS = full 256x256 u16 histogram.
// Output: hist16[part][b][32768 u32 words] (u16 pairs, even bin = low half).
// ---------------------------------------------------------------------------
__global__ __launch_bounds__(1024) void k_grayhist(const float* __restrict__ img,
                                                   uint32_t* __restrict__ hist16) {
    __shared__ uint32_t lh[32768];               // 128 KB packed u16 counts
    const int part = blockIdx.x & 3;
    const int b    = blockIdx.x >> 2;
    const int t    = threadIdx.x;
    const int w    = t >> 6;                     // wave 0..15
    const int lane = t & 63;

    {   // zero LDS
        uint4* lh4 = (uint4*)lh;
        for (int k = t; k < 8192; k += 1024) lh4[k] = make_uint4(0, 0, 0, 0);
    }
    __syncthreads();

    const int row0 = part * 128;
#pragma unroll 1
    for (int it = 0; it < 8; ++it) {
        const int row = row0 + (it << 4) + w;
        const size_t ibase = ((size_t)(b * 3) * NH + row) * NW;
        const float4* pR = (const float4*)(img + ibase);
        const float4* pG = (const float4*)(img + ibase + PLANE);
        const float4* pB = (const float4*)(img + ibase + 2 * (size_t)PLANE);
        float4 r0 = pR[2 * lane], r1 = pR[2 * lane + 1];
        float4 g0 = pG[2 * lane], g1 = pG[2 * lane + 1];
        float4 b0 = pB[2 * lane], b1 = pB[2 * lane + 1];

        float rr[8] = {r0.x, r0.y, r0.z, r0.w, r1.x, r1.y, r1.z, r1.w};
        float gg[8] = {g0.x, g0.y, g0.z, g0.w, g1.x, g1.y, g1.z, g1.w};
        float bb[8] = {b0.x, b0.y, b0.z, b0.w, b1.x, b1.y, b1.z, b1.w};

        uint32_t gi[8];
#pragma unroll
        for (int k = 0; k < 8; ++k) {
            float qr = fminf(fmaxf(floorf(__fmul_rn(rr[k], 255.0f)), 0.0f), 255.0f);
            float qg = fminf(fmaxf(floorf(__fmul_rn(gg[k], 255.0f)), 0.0f), 255.0f);
            float qb = fminf(fmaxf(floorf(__fmul_rn(bb[k], 255.0f)), 0.0f), 255.0f);
            float gy = __fadd_rn(__fadd_rn(__fmul_rn(0.299f, qr),
                                           __fmul_rn(0.587f, qg)),
                                 __fmul_rn(0.114f, qb));
            int v = (int)rintf(gy);              // round half to even == jnp.round
            gi[k] = (uint32_t)(v < 0 ? 0 : (v > 255 ? 255 : v));
        }
        uint32_t w0 = gi[0] | (gi[1] << 8) | (gi[2] << 16) | (gi[3] << 24);
        uint32_t w1 = gi[4] | (gi[5] << 8) | (gi[6] << 16) | (gi[7] << 24);
        uint32_t nw0 = __shfl(w0, lane + 1, 64); // lane63: only k<3 used
        uint32_t nw1 = __shfl(w1, lane + 1, 64);
        // j bytes aligned to i position k: col(8*lane+k)+5
        uint32_t jlo = (w1 >> 8) | (nw0 << 24);  // k=0..3
        uint32_t jhi = (nw0 >> 8) | (nw1 << 24); // k=4..7
        const int np = (lane == 63) ? 3 : 8;     // cols <= 506 pair-valid
#pragma unroll
        for (int k = 0; k < 8; ++k) {
            if (k < np) {
                uint32_t j = ((k < 4) ? (jlo >> (8 * k)) : (jhi >> (8 * (k - 4)))) & 255u;
                uint32_t bin = (gi[k] << 8) | j;
                atomicAdd(&lh[bin >> 1], 1u << ((bin & 1u) << 4));
            }
        }
    }
    __syncthreads();

    uint4* dst = (uint4*)(hist16 + (((size_t)(part * NB + b)) << 15));
    const uint4* src = (const uint4*)lh;
    for (int k = t; k < 8192; k += 1024) dst[k] = src[k];
}

// ---------------------------------------------------------------------------
// K2: moments. grid = 64 batches x 32 i-slices (8 rows each), 256 threads.
// Thread t owns bins (i = i0+k, j = t), k=0..7, summing 4 u16 parts.
//   cf: coalesced word loads (2 lanes share a word -> broadcast)
//   ct: 1 uint4 per part = 4 consecutive words (energy transpose term)
// Exact u64 integer moments + f32 homogeneity table; 7 doubles per WG.
// ---------------------------------------------------------------------------
__global__ __launch_bounds__(256) void k_moms(const uint32_t* __restrict__ hist16,
                                              double* __restrict__ partials) {
    __shared__ float whom[256];
    const int b  = blockIdx.x >> 5;
    const int sl = blockIdx.x & 31;
    const int i0 = sl * 8;
    const int t  = threadIdx.x;

    whom[t] = 1.0f / (float)(1 + t * t);
    __syncthreads();

    uint32_t cf[8], ct[8];
#pragma unroll
    for (int k = 0; k < 8; ++k) { cf[k] = 0; ct[k] = 0; }

#pragma unroll
    for (int p = 0; p < NPARTS; ++p) {
        const uint32_t* hp = hist16 + (((size_t)(p * NB + b)) << 15);
        const int sh = (t & 1) * 16;
#pragma unroll
        for (int k = 0; k < 8; ++k)
            cf[k] += (hp[(i0 + k) * 128 + (t >> 1)] >> sh) & 0xFFFFu;
        uint4 v = *(const uint4*)(hp + t * 128 + (i0 >> 1));
        ct[0] += v.x & 0xFFFFu; ct[1] += v.x >> 16;
        ct[2] += v.y & 0xFFFFu; ct[3] += v.y >> 16;
        ct[4] += v.z & 0xFFFFu; ct[5] += v.z >> 16;
        ct[6] += v.w & 0xFFFFu; ct[7] += v.w >> 16;
    }

    unsigned long long A_con = 0, A_dis = 0, A_e = 0;
    unsigned long long A_s1 = 0, A_s2 = 0, A_sij = 0;
    float A_homf = 0.0f;

#pragma unroll
    for (int k = 0; k < 8; ++k) {
        int i  = i0 + k;
        int j  = t;
        int d  = i - j;
        uint32_t ad = (uint32_t)(d < 0 ? -d : d);
        uint32_t dd = ad * ad;
        uint32_t c  = cf[k];
        A_con += (unsigned long long)c * dd;
        A_dis += (unsigned long long)c * ad;
        A_e   += (unsigned long long)c * c + (unsigned long long)c * ct[k];
        A_s1  += (unsigned long long)c * (uint32_t)(i + j);
        A_s2  += (unsigned long long)c * (uint32_t)(i * i + j * j);
        A_sij += (unsigned long long)c * (uint32_t)(i * j);
        A_homf += (float)c * whom[ad];
    }

    double acc[7] = {(double)A_con, (double)A_dis, (double)A_homf,
                     (double)A_e, (double)A_s1, (double)A_s2, (double)A_sij};
#pragma unroll
    for (int a = 0; a < 7; ++a) {
#pragma unroll
        for (int off = 32; off; off >>= 1)
            acc[a] += __shfl_down(acc[a], off, 64);
    }
    __shared__ double sred[7][4];
    int wid = t >> 6, lane = t & 63;
    if (lane == 0) {
#pragma unroll
        for (int a = 0; a < 7; ++a) sred[a][wid] = acc[a];
    }
    __syncthreads();
    if (t < 7)
        partials[(size_t)blockIdx.x * 7 + t] =
            sred[t][0] + sred[t][1] + sred[t][2] + sred[t][3];
}

// ---------------------------------------------------------------------------
// K3: final reduce + features. grid = 64, block = 64 (one wave).
// ---------------------------------------------------------------------------
__global__ __launch_bounds__(64) void k_final(const double* __restrict__ partials,
                                              float* __restrict__ out) {
    int b = blockIdx.x;
    int lane = threadIdx.x;

    double v[7];
#pragma unroll
    for (int a = 0; a < 7; ++a) {
        double x = (lane < 32) ? partials[(size_t)(b * 32 + lane) * 7 + a] : 0.0;
#pragma unroll
        for (int off = 32; off; off >>= 1)
            x += __shfl_down(x, off, 64);
        v[a] = x;
    }

    if (lane == 0) {
        const double T = 2.0 * (double)NPAIRS;   // symmetrized total
        double contrast = 2.0 * v[0] / T;
        double dissim   = 2.0 * v[1] / T;
        double homog    = 2.0 * v[2] / T;
        double energy   = sqrt(2.0 * v[3]) / T;
        double mu    = v[4] / T;                 // mu_i == mu_j (symmetric)
        double var   = v[5] / T - mu * mu;
        double cov   = 2.0 * v[6] / T - mu * mu;
        double sd    = sqrt(var * var);
        double corr  = (sd < 1e-15) ? 1.0 : cov / fmax(sd, 1e-15);

        float f[5] = {(float)contrast, (float)dissim, (float)homog,
                      (float)energy, (float)corr};
        float mn = f[0], mx = f[0];
#pragma unroll
        for (int k = 1; k < 5; ++k) { mn = fminf(mn, f[k]); mx = fmaxf(mx, f[k]); }
        float rng = mx - mn;
#pragma unroll
        for (int k = 0; k < 5; ++k) {
            float fn = (f[k] - mn) / rng;
            float q8 = floorf(__fmul_rn(fn, 255.0f));
            float val = q8 / 255.0f;
            out[b * 15 + 0 * 5 + k] = val;
            out[b * 15 + 1 * 5 + k] = val;
            out[b * 15 + 2 * 5 + k] = val;
        }
    }
}

// ---------------------------------------------------------------------------
extern "C" void kernel_launch(void* const* d_in, const int* in_sizes, int n_in,
                              void* d_out, int out_size, void* d_ws, size_t ws_size,
                              hipStream_t stream) {
    const float* img = (const float*)d_in[0];
    float* out = (float*)d_out;

    // hist16: 4 parts x 64 b x 128KB = 32 MB; partials after (2048*7*8 = 114KB)
    uint32_t* hist16 = (uint32_t*)d_ws;
    double* partials = (double*)((char*)d_ws + ((size_t)32 << 20));

    k_grayhist<<<NB * NPARTS, 1024, 0, stream>>>(img, hist16);
    k_moms<<<NB * 32, 256, 0, stream>>>(hist16, partials);
    k_final<<<NB, 64, 0, stream>>>(partials, out);
}

// Round 7
// 55.463 us; speedup vs baseline: 1.5101x; 1.5101x over previous
//
#include <hip/hip_runtime.h>
#include <stdint.h>

#define NLEV   256
#define DIST   5
#define NB     64
#define NH     512
#define NW     512
#define PLANE  (NH*NW)            // 262144
#define NPAIRS (NH*(NW-DIST))     // 259584
#define NPARTS 4                  // 128 rows/part; sym-hist expected max bin ~16 << 65535 (u16-safe)

// ---------------------------------------------------------------------------
// K1 (fused gray+hist, SYMMETRIZED): grid = 64 batches x 4 row-parts,
// 1024 threads. One wave per row-iteration: lane owns 8 px, gray in regs,
// col+5 neighbor via __shfl, TWO packed-u16 LDS atomics per pair:
// bins (i,j) AND (j,i)  ->  LDS accumulates S = C + C^T directly
// (diagonal doubled, matching glcm + glcm.T). No transpose pass needed
// downstream. Output: hist16[part][b][32768 u32 words] (u16 bin pairs).
// ---------------------------------------------------------------------------
__global__ __launch_bounds__(1024) void k_grayhist(const float* __restrict__ img,
                                                   uint32_t* __restrict__ hist16) {
    __shared__ uint32_t lh[32768];               // 128 KB packed u16 counts
    const int part = blockIdx.x & 3;
    const int b    = blockIdx.x >> 2;
    const int t    = threadIdx.x;
    const int w    = t >> 6;                     // wave 0..15
    const int lane = t & 63;

    {   // zero LDS
        uint4* lh4 = (uint4*)lh;
        for (int k = t; k < 8192; k += 1024) lh4[k] = make_uint4(0, 0, 0, 0);
    }
    __syncthreads();

    const int row0 = part * 128;
#pragma unroll 1
    for (int it = 0; it < 8; ++it) {
        const int row = row0 + (it << 4) + w;
        const size_t ibase = ((size_t)(b * 3) * NH + row) * NW;
        const float4* pR = (const float4*)(img + ibase);
        const float4* pG = (const float4*)(img + ibase + PLANE);
        const float4* pB = (const float4*)(img + ibase + 2 * (size_t)PLANE);
        float4 r0 = pR[2 * lane], r1 = pR[2 * lane + 1];
        float4 g0 = pG[2 * lane], g1 = pG[2 * lane + 1];
        float4 b0 = pB[2 * lane], b1 = pB[2 * lane + 1];

        float rr[8] = {r0.x, r0.y, r0.z, r0.w, r1.x, r1.y, r1.z, r1.w};
        float gg[8] = {g0.x, g0.y, g0.z, g0.w, g1.x, g1.y, g1.z, g1.w};
        float bb[8] = {b0.x, b0.y, b0.z, b0.w, b1.x, b1.y, b1.z, b1.w};

        uint32_t gi[8];
#pragma unroll
        for (int k = 0; k < 8; ++k) {
            float qr = fminf(fmaxf(floorf(__fmul_rn(rr[k], 255.0f)), 0.0f), 255.0f);
            float qg = fminf(fmaxf(floorf(__fmul_rn(gg[k], 255.0f)), 0.0f), 255.0f);
            float qb = fminf(fmaxf(floorf(__fmul_rn(bb[k], 255.0f)), 0.0f), 255.0f);
            float gy = __fadd_rn(__fadd_rn(__fmul_rn(0.299f, qr),
                                           __fmul_rn(0.587f, qg)),
                                 __fmul_rn(0.114f, qb));
            int v = (int)rintf(gy);              // round half to even == jnp.round
            gi[k] = (uint32_t)(v < 0 ? 0 : (v > 255 ? 255 : v));
        }
        uint32_t w0 = gi[0] | (gi[1] << 8) | (gi[2] << 16) | (gi[3] << 24);
        uint32_t w1 = gi[4] | (gi[5] << 8) | (gi[6] << 16) | (gi[7] << 24);
        uint32_t nw0 = __shfl(w0, lane + 1, 64); // lane63: only k<3 used
        uint32_t nw1 = __shfl(w1, lane + 1, 64);
        // j bytes aligned to i position k: col(8*lane+k)+5
        uint32_t jlo = (w1 >> 8) | (nw0 << 24);  // k=0..3
        uint32_t jhi = (nw0 >> 8) | (nw1 << 24); // k=4..7
        const int np = (lane == 63) ? 3 : 8;     // cols <= 506 pair-valid
#pragma unroll
        for (int k = 0; k < 8; ++k) {
            if (k < np) {
                uint32_t j = ((k < 4) ? (jlo >> (8 * k)) : (jhi >> (8 * (k - 4)))) & 255u;
                uint32_t bin1 = (gi[k] << 8) | j;        // (i,j)
                uint32_t bin2 = (j << 8) | gi[k];        // (j,i)
                atomicAdd(&lh[bin1 >> 1], 1u << ((bin1 & 1u) << 4));
                atomicAdd(&lh[bin2 >> 1], 1u << ((bin2 & 1u) << 4));
            }
        }
    }
    __syncthreads();

    uint4* dst = (uint4*)(hist16 + (((size_t)(part * NB + b)) << 15));
    const uint4* src = (const uint4*)lh;
    for (int k = t; k < 8192; k += 1024) dst[k] = src[k];
}

// ---------------------------------------------------------------------------
// K2: moments over the symmetrized S. grid = 64 batches x 32 slices (8 rows),
// 256 threads. Thread t owns one uint4 per part at word offset slice*1024+4t:
// 8 bins, single i = i0 + (t>>5), consecutive j = (t&31)*8 + e. Fully
// coalesced; parts summed BEFORE squaring (energy needs total S). Exact u64
// integer moments + f32 homogeneity table; 7 doubles per WG.
// ---------------------------------------------------------------------------
__global__ __launch_bounds__(256) void k_moms(const uint32_t* __restrict__ hist16,
                                              double* __restrict__ partials) {
    __shared__ float whom[256];
    const int b  = blockIdx.x >> 5;
    const int sl = blockIdx.x & 31;
    const int t  = threadIdx.x;

    whom[t] = 1.0f / (float)(1 + t * t);
    __syncthreads();

    const int wbase = (sl << 10) + (t << 2);     // u32-word offset within batch hist
    uint32_t s8[8] = {0, 0, 0, 0, 0, 0, 0, 0};
#pragma unroll
    for (int p = 0; p < NPARTS; ++p) {
        const uint32_t* hp = hist16 + (((size_t)(p * NB + b)) << 15) + wbase;
        uint4 v = *(const uint4*)hp;
        s8[0] += v.x & 0xFFFFu; s8[1] += v.x >> 16;
        s8[2] += v.y & 0xFFFFu; s8[3] += v.y >> 16;
        s8[4] += v.z & 0xFFFFu; s8[5] += v.z >> 16;
        s8[6] += v.w & 0xFFFFu; s8[7] += v.w >> 16;
    }

    const int i  = (sl << 3) + (t >> 5);
    const int j0 = (t & 31) << 3;

    unsigned long long A_con = 0, A_dis = 0, A_e = 0;
    unsigned long long A_si = 0, A_sii = 0, A_sij = 0;
    float A_hom = 0.0f;

#pragma unroll
    for (int e = 0; e < 8; ++e) {
        int j = j0 + e;
        int d = i - j;
        uint32_t ad = (uint32_t)(d < 0 ? -d : d);
        uint32_t s  = s8[e];
        A_con += (unsigned long long)s * (ad * ad);
        A_dis += (unsigned long long)s * ad;
        A_e   += (unsigned long long)s * s;
        A_si  += (unsigned long long)s * (uint32_t)i;
        A_sii += (unsigned long long)s * (uint32_t)(i * i);
        A_sij += (unsigned long long)s * (uint32_t)(i * j);
        A_hom += (float)s * whom[ad];
    }

    double acc[7] = {(double)A_con, (double)A_dis, (double)A_hom,
                     (double)A_e, (double)A_si, (double)A_sii, (double)A_sij};
#pragma unroll
    for (int a = 0; a < 7; ++a) {
#pragma unroll
        for (int off = 32; off; off >>= 1)
            acc[a] += __shfl_down(acc[a], off, 64);
    }
    __shared__ double sred[7][4];
    int wid = t >> 6, lane = t & 63;
    if (lane == 0) {
#pragma unroll
        for (int a = 0; a < 7; ++a) sred[a][wid] = acc[a];
    }
    __syncthreads();
    if (t < 7)
        partials[(size_t)blockIdx.x * 7 + t] =
            sred[t][0] + sred[t][1] + sred[t][2] + sred[t][3];
}

// ---------------------------------------------------------------------------
// K3: final reduce + features. grid = 64, block = 64 (one wave).
// v = {con, dis, hom, e, si, sii, sij} summed over the symmetrized S.
// ---------------------------------------------------------------------------
__global__ __launch_bounds__(64) void k_final(const double* __restrict__ partials,
                                              float* __restrict__ out) {
    int b = blockIdx.x;
    int lane = threadIdx.x;

    double v[7];
#pragma unroll
    for (int a = 0; a < 7; ++a) {
        double x = (lane < 32) ? partials[(size_t)(b * 32 + lane) * 7 + a] : 0.0;
#pragma unroll
        for (int off = 32; off; off >>= 1)
            x += __shfl_down(x, off, 64);
        v[a] = x;
    }

    if (lane == 0) {
        const double T = 2.0 * (double)NPAIRS;   // total of symmetrized S
        double contrast = v[0] / T;
        double dissim   = v[1] / T;
        double homog    = v[2] / T;
        double energy   = sqrt(v[3]) / T;
        double mu    = v[4] / T;                 // mu_i == mu_j (S symmetric)
        double var   = v[5] / T - mu * mu;
        double cov   = v[6] / T - mu * mu;
        double sd    = sqrt(var * var);          // = sqrt(var_i*var_j)
        double corr  = (sd < 1e-15) ? 1.0 : cov / fmax(sd, 1e-15);

        float f[5] = {(float)contrast, (float)dissim, (float)homog,
                      (float)energy, (float)corr};
        float mn = f[0], mx = f[0];
#pragma unroll
        for (int k = 1; k < 5; ++k) { mn = fminf(mn, f[k]); mx = fmaxf(mx, f[k]); }
        float rng = mx - mn;
#pragma unroll
        for (int k = 0; k < 5; ++k) {
            float fn = (f[k] - mn) / rng;
            float q8 = floorf(__fmul_rn(fn, 255.0f));
            float val = q8 / 255.0f;
            out[b * 15 + 0 * 5 + k] = val;
            out[b * 15 + 1 * 5 + k] = val;
            out[b * 15 + 2 * 5 + k] = val;
        }
    }
}

// ---------------------------------------------------------------------------
extern "C" void kernel_launch(void* const* d_in, const int* in_sizes, int n_in,
                              void* d_out, int out_size, void* d_ws, size_t ws_size,
                              hipStream_t stream) {
    const float* img = (const float*)d_in[0];
    float* out = (float*)d_out;

    // hist16: 4 parts x 64 b x 128KB = 32 MB; partials after (2048*7*8 = 114KB)
    uint32_t* hist16 = (uint32_t*)d_ws;
    double* partials = (double*)((char*)d_ws + ((size_t)32 << 20));

    k_grayhist<<<NB * NPARTS, 1024, 0, stream>>>(img, hist16);
    k_moms<<<NB * 32, 256, 0, stream>>>(hist16, partials);
    k_final<<<NB, 64, 0, stream>>>(partials, out);
}

// Round 8
// 51.907 us; speedup vs baseline: 1.6136x; 1.0685x over previous
//
#include <hip/hip_runtime.h>
#include <stdint.h>

#define NLEV   256
#define DIST   5
#define NB     64
#define NH     512
#define NW     512
#define PLANE  (NH*NW)            // 262144
#define NPAIRS (NH*(NW-DIST))     // 259584
#define NPARTS 4                  // 128 rows/part: max 2*64896 sym-counts/bin < 65536 (u16-safe, any input)

// ---------------------------------------------------------------------------
// K1 (fused gray+hist+linear-moments): grid = 64 batches x 4 row-parts,
// 1024 threads. Wave per row: lane owns 8 px, gray in regs, col+5 neighbor
// via __shfl, two packed-u16 LDS atomics per pair -> LDS holds the
// symmetrized S_p = C_p + C_p^T. Then: (a) store S_p to global (needed only
// for energy's cross-part term), (b) compute the 6 LINEAR moments of S_p
// straight from LDS (they sum across parts) -> 6 doubles.
// ---------------------------------------------------------------------------
__global__ __launch_bounds__(1024) void k_grayhist(const float* __restrict__ img,
                                                   uint32_t* __restrict__ hist16,
                                                   double* __restrict__ lin) {
    __shared__ uint32_t lh[32768];               // 128 KB packed u16 counts
    __shared__ float whom[256];
    __shared__ double sred[6][16];
    const int part = blockIdx.x & 3;
    const int b    = blockIdx.x >> 2;
    const int t    = threadIdx.x;
    const int w    = t >> 6;                     // wave 0..15
    const int lane = t & 63;

    {   // zero LDS hist + homogeneity weight table
        uint4* lh4 = (uint4*)lh;
        for (int k = t; k < 8192; k += 1024) lh4[k] = make_uint4(0, 0, 0, 0);
        if (t < 256) whom[t] = 1.0f / (float)(1 + t * t);
    }
    __syncthreads();

    const int row0 = part * 128;
#pragma unroll 1
    for (int it = 0; it < 8; ++it) {
        const int row = row0 + (it << 4) + w;
        const size_t ibase = ((size_t)(b * 3) * NH + row) * NW;
        const float4* pR = (const float4*)(img + ibase);
        const float4* pG = (const float4*)(img + ibase + PLANE);
        const float4* pB = (const float4*)(img + ibase + 2 * (size_t)PLANE);
        float4 r0 = pR[2 * lane], r1 = pR[2 * lane + 1];
        float4 g0 = pG[2 * lane], g1 = pG[2 * lane + 1];
        float4 b0 = pB[2 * lane], b1 = pB[2 * lane + 1];

        float rr[8] = {r0.x, r0.y, r0.z, r0.w, r1.x, r1.y, r1.z, r1.w};
        float gg[8] = {g0.x, g0.y, g0.z, g0.w, g1.x, g1.y, g1.z, g1.w};
        float bb[8] = {b0.x, b0.y, b0.z, b0.w, b1.x, b1.y, b1.z, b1.w};

        uint32_t gi[8];
#pragma unroll
        for (int k = 0; k < 8; ++k) {
            float qr = fminf(fmaxf(floorf(__fmul_rn(rr[k], 255.0f)), 0.0f), 255.0f);
            float qg = fminf(fmaxf(floorf(__fmul_rn(gg[k], 255.0f)), 0.0f), 255.0f);
            float qb = fminf(fmaxf(floorf(__fmul_rn(bb[k], 255.0f)), 0.0f), 255.0f);
            float gy = __fadd_rn(__fadd_rn(__fmul_rn(0.299f, qr),
                                           __fmul_rn(0.587f, qg)),
                                 __fmul_rn(0.114f, qb));
            int v = (int)rintf(gy);              // round half to even == jnp.round
            gi[k] = (uint32_t)(v < 0 ? 0 : (v > 255 ? 255 : v));
        }
        uint32_t w0 = gi[0] | (gi[1] << 8) | (gi[2] << 16) | (gi[3] << 24);
        uint32_t w1 = gi[4] | (gi[5] << 8) | (gi[6] << 16) | (gi[7] << 24);
        uint32_t nw0 = __shfl(w0, lane + 1, 64); // lane63: only k<3 used
        uint32_t nw1 = __shfl(w1, lane + 1, 64);
        uint32_t jlo = (w1 >> 8) | (nw0 << 24);  // j bytes, k=0..3
        uint32_t jhi = (nw0 >> 8) | (nw1 << 24); // k=4..7
        const int np = (lane == 63) ? 3 : 8;     // cols <= 506 pair-valid
#pragma unroll
        for (int k = 0; k < 8; ++k) {
            if (k < np) {
                uint32_t j = ((k < 4) ? (jlo >> (8 * k)) : (jhi >> (8 * (k - 4)))) & 255u;
                uint32_t bin1 = (gi[k] << 8) | j;        // (i,j)
                uint32_t bin2 = (j << 8) | gi[k];        // (j,i)
                atomicAdd(&lh[bin1 >> 1], 1u << ((bin1 & 1u) << 4));
                atomicAdd(&lh[bin2 >> 1], 1u << ((bin2 & 1u) << 4));
            }
        }
    }
    __syncthreads();

    // (a) store S_p for the energy pass (fire-and-forget stores)
    uint4* dst = (uint4*)(hist16 + (((size_t)(part * NB + b)) << 15));
    const uint4* src = (const uint4*)lh;
    for (int k = t; k < 8192; k += 1024) dst[k] = src[k];

    // (b) linear moments of S_p from LDS (overlaps with store drain).
    // word wd = i*128 + j/2 holds bins (i, 2*(wd&127)) and (i, 2*(wd&127)+1).
    unsigned long long M_con = 0, M_dis = 0, M_si = 0, M_sii = 0, M_sij = 0;
    float M_hom = 0.0f;
#pragma unroll 1
    for (int it = 0; it < 16; ++it) {
        int wd = (it << 10) + t;                 // conflict-free: lane-consecutive
        uint32_t v = lh[wd];
        int i  = wd >> 7;
        int j0 = (wd & 127) << 1;
        uint32_t s0 = v & 0xFFFFu, s1 = v >> 16;
        int d0 = i - j0, d1 = i - (j0 + 1);
        uint32_t ad0 = (uint32_t)(d0 < 0 ? -d0 : d0);
        uint32_t ad1 = (uint32_t)(d1 < 0 ? -d1 : d1);
        M_con += (unsigned long long)s0 * (ad0 * ad0)
               + (unsigned long long)s1 * (ad1 * ad1);
        M_dis += (unsigned long long)s0 * ad0 + (unsigned long long)s1 * ad1;
        M_si  += (unsigned long long)(s0 + s1) * (uint32_t)i;
        M_sii += (unsigned long long)(s0 + s1) * (uint32_t)(i * i);
        M_sij += (unsigned long long)s0 * (uint32_t)(i * j0)
               + (unsigned long long)s1 * (uint32_t)(i * (j0 + 1));
        M_hom += (float)s0 * whom[ad0] + (float)s1 * whom[ad1];
    }

    double acc[6] = {(double)M_con, (double)M_dis, (double)M_hom,
                     (double)M_si, (double)M_sii, (double)M_sij};
#pragma unroll
    for (int a = 0; a < 6; ++a) {
#pragma unroll
        for (int off = 32; off; off >>= 1)
            acc[a] += __shfl_down(acc[a], off, 64);
    }
    if (lane == 0) {
#pragma unroll
        for (int a = 0; a < 6; ++a) sred[a][w] = acc[a];
    }
    __syncthreads();
    if (t < 6) {
        double s = 0.0;
#pragma unroll
        for (int k = 0; k < 16; ++k) s += sred[t][k];
        lin[(size_t)(part * NB + b) * 6 + t] = s;
    }
}

// ---------------------------------------------------------------------------
// K2 (energy only): grid = 64 batches x 4 word-quarters, 256 threads.
// E_q = sum over its 8192 words of (sum_p S_p)^2 per u16 half — halves MUST
// be unpacked before summing parts (4*65535 > 65535). Exact u64.
// ---------------------------------------------------------------------------
__global__ __launch_bounds__(256) void k_energy(const uint32_t* __restrict__ hist16,
                                                double* __restrict__ en) {
    const int b = blockIdx.x >> 2;
    const int q = blockIdx.x & 3;
    const int t = threadIdx.x;

    unsigned long long acc = 0;
#pragma unroll
    for (int it = 0; it < 4; ++it) {
        const int wbase = (q << 12) + (it << 10) + (t << 2);
        uint32_t lo[8] = {0,0,0,0,0,0,0,0}, hi[8];
#pragma unroll
        for (int k = 0; k < 8; ++k) hi[k] = 0;  // silence
#pragma unroll
        for (int p = 0; p < NPARTS; ++p) {
            uint4 v = *(const uint4*)(hist16 + (((size_t)(p * NB + b)) << 15) + wbase);
            lo[0] += v.x & 0xFFFFu; lo[1] += v.x >> 16;
            lo[2] += v.y & 0xFFFFu; lo[3] += v.y >> 16;
            lo[4] += v.z & 0xFFFFu; lo[5] += v.z >> 16;
            lo[6] += v.w & 0xFFFFu; lo[7] += v.w >> 16;
        }
#pragma unroll
        for (int k = 0; k < 8; ++k)
            acc += (unsigned long long)lo[k] * lo[k];
    }

    double x = (double)acc;
#pragma unroll
    for (int off = 32; off; off >>= 1)
        x += __shfl_down(x, off, 64);
    __shared__ double sr[4];
    if ((t & 63) == 0) sr[t >> 6] = x;
    __syncthreads();
    if (t == 0) en[blockIdx.x] = sr[0] + sr[1] + sr[2] + sr[3];
}

// ---------------------------------------------------------------------------
// K3: final features. grid = 64, block = 64; lane 0 does the tiny combine.
// ---------------------------------------------------------------------------
__global__ __launch_bounds__(64) void k_final(const double* __restrict__ lin,
                                              const double* __restrict__ en,
                                              float* __restrict__ out) {
    int b = blockIdx.x;
    if (threadIdx.x == 0) {
        double v[6] = {0, 0, 0, 0, 0, 0};
#pragma unroll
        for (int p = 0; p < NPARTS; ++p)
#pragma unroll
            for (int a = 0; a < 6; ++a)
                v[a] += lin[(size_t)(p * NB + b) * 6 + a];
        double E = en[b * 4] + en[b * 4 + 1] + en[b * 4 + 2] + en[b * 4 + 3];

        const double T = 2.0 * (double)NPAIRS;   // total of symmetrized S
        double contrast = v[0] / T;
        double dissim   = v[1] / T;
        double homog    = v[2] / T;
        double energy   = sqrt(E) / T;
        double mu    = v[3] / T;                 // mu_i == mu_j (S symmetric)
        double var   = v[4] / T - mu * mu;
        double cov   = v[5] / T - mu * mu;
        double sd    = sqrt(var * var);          // = sqrt(var_i*var_j)
        double corr  = (sd < 1e-15) ? 1.0 : cov / fmax(sd, 1e-15);

        float f[5] = {(float)contrast, (float)dissim, (float)homog,
                      (float)energy, (float)corr};
        float mn = f[0], mx = f[0];
#pragma unroll
        for (int k = 1; k < 5; ++k) { mn = fminf(mn, f[k]); mx = fmaxf(mx, f[k]); }
        float rng = mx - mn;
#pragma unroll
        for (int k = 0; k < 5; ++k) {
            float fn = (f[k] - mn) / rng;
            float q8 = floorf(__fmul_rn(fn, 255.0f));
            float val = q8 / 255.0f;
            out[b * 15 + 0 * 5 + k] = val;
            out[b * 15 + 1 * 5 + k] = val;
            out[b * 15 + 2 * 5 + k] = val;
        }
    }
}

// ---------------------------------------------------------------------------
extern "C" void kernel_launch(void* const* d_in, const int* in_sizes, int n_in,
                              void* d_out, int out_size, void* d_ws, size_t ws_size,
                              hipStream_t stream) {
    const float* img = (const float*)d_in[0];
    float* out = (float*)d_out;

    // hist16: 4 x 64 x 128KB = 32 MB; lin: 4*64*6 doubles; en: 256 doubles
    uint32_t* hist16 = (uint32_t*)d_ws;
    double* lin = (double*)((char*)d_ws + ((size_t)32 << 20));
    double* en  = lin + (size_t)NPARTS * NB * 6;

    k_grayhist<<<NB * NPARTS, 1024, 0, stream>>>(img, hist16, lin);
    k_energy<<<NB * 4, 256, 0, stream>>>(hist16, en);
    k_final<<<NB, 64, 0, stream>>>(lin, en, out);
}